// Round 9
// baseline (61.265 us; speedup 1.0000x reference)
//
#include <hip/hip_runtime.h>

#define N2   8192
#define NTRI 2080 // 64*65/2 upper-triangle 128x128 blocks

static constexpr float INV_T = 1.0f / 0.07f;

using f32x4 = __attribute__((ext_vector_type(4))) float;
using i32x4 = __attribute__((ext_vector_type(4))) int;
using i32x8 = __attribute__((ext_vector_type(8))) int;
typedef unsigned int u32;

#define SCALE1 0x7F7F7F7F   // E8M0 127 = 2^0 in every byte -> scale 1.0

// ---------- kernel 1: normalize rows, f32 -> fp8 e4m3 (OCP); also zero counter ----------
__global__ void ntx_norm(const float* __restrict__ z1, const float* __restrict__ z2,
                         unsigned char* __restrict__ zn, u32* __restrict__ counter)
{
    if (blockIdx.x == 0 && threadIdx.x == 0) *counter = 0;   // visible to ntx_loss (kernel boundary)

    const int w    = threadIdx.x >> 6;
    const int lane = threadIdx.x & 63;
    const int row  = blockIdx.x * 4 + w;

    const float* src = (row < 4096) ? (z1 + (size_t)row * 256)
                                    : (z2 + (size_t)(row - 4096) * 256);
    float4 v = *(const float4*)(src + lane * 4);
    float ss = v.x * v.x + v.y * v.y + v.z * v.z + v.w * v.w;
    #pragma unroll
    for (int m = 1; m < 64; m <<= 1) ss += __shfl_xor(ss, m, 64);

    float inv = 1.0f / fmaxf(sqrtf(ss), 1e-8f);

    u32 p = __builtin_amdgcn_cvt_pk_fp8_f32(v.x * inv, v.y * inv, 0u, false);
    p     = __builtin_amdgcn_cvt_pk_fp8_f32(v.z * inv, v.w * inv, p, true);
    ((u32*)zn)[(size_t)row * 64 + lane] = p;
}

// ---------- kernel 2: upper-triangle sim blocks, MX-scaled fp8 MFMA (K=128) ----------
// ZERO LDS, ZERO barriers: zn (2 MB) is L2-resident on every XCD, so MFMA
// fragments (32 B/lane) are loaded straight from global into VGPRs as two
// dwordx4 each. 128x128 tile, 4 waves (2x2), wave tile 64x64, 2 K-tiles.
// Waves free-run at natural phase offsets -> cross-wave MFMA/VALU/load overlap.
__global__ __launch_bounds__(256)
void ntx_gemm(const unsigned char* __restrict__ zn, float* __restrict__ partials,
              float* __restrict__ pos)
{
    const int tid  = threadIdx.x;
    const int lane = tid & 63;
    const int w    = tid >> 6;       // 0..3
    const int wr   = w >> 1;         // 0..1
    const int wc   = w & 1;          // 0..1

    // triangle decode: blockIdx.x -> (br, bc), br <= bc
    const int t = (int)blockIdx.x;
    int br = (int)((129.0f - sqrtf(16641.0f - 8.0f * (float)t)) * 0.5f);
    while ((br + 1) * (129 - (br + 1)) / 2 <= t) ++br;
    while (br * (129 - br) / 2 > t) --br;
    const int bc = br + (t - br * (129 - br) / 2);

    const int fr = lane & 15;        // fragment row/col
    const int kl = lane >> 4;        // k-group 0..3 (32 B each)

    // per-lane fragment base addresses (row-major zn, 256 B/row)
    const char* baseA = (const char*)zn + (size_t)(br * 128 + wr * 64 + fr) * 256 + kl * 32;
    const char* baseB = (const char*)zn + (size_t)(bc * 128 + wc * 64 + fr) * 256 + kl * 32;

    f32x4 acc[4][4] = {};

    #pragma unroll
    for (int kt = 0; kt < 2; ++kt) {
        i32x8 af[4], bv[4];
        #pragma unroll
        for (int mf = 0; mf < 4; ++mf) {
            const char* p = baseA + mf * 4096 + kt * 128;   // +16 rows = 4096 B
            i32x4 lo = *(const i32x4*)(p);
            i32x4 hi = *(const i32x4*)(p + 16);
            af[mf] = (i32x8){lo[0], lo[1], lo[2], lo[3], hi[0], hi[1], hi[2], hi[3]};
        }
        #pragma unroll
        for (int nf = 0; nf < 4; ++nf) {
            const char* p = baseB + nf * 4096 + kt * 128;
            i32x4 lo = *(const i32x4*)(p);
            i32x4 hi = *(const i32x4*)(p + 16);
            bv[nf] = (i32x8){lo[0], lo[1], lo[2], lo[3], hi[0], hi[1], hi[2], hi[3]};
        }
        __builtin_amdgcn_s_setprio(1);
        #pragma unroll
        for (int mf = 0; mf < 4; ++mf)
            #pragma unroll
            for (int nf = 0; nf < 4; ++nf)
                acc[mf][nf] = __builtin_amdgcn_mfma_scale_f32_16x16x128_f8f6f4(
                    af[mf], bv[nf], acc[mf][nf], 0, 0, 0, SCALE1, 0, SCALE1);
        __builtin_amdgcn_s_setprio(0);
    }

    // ---- epilogue (R2-proven; C/D layout shape-determined) ----
    // e = exp((dot-1)/T), diag masked. Row sums -> partials[row][2*bc+wc];
    // off-diag blocks add transpose col sums -> partials[col][2*br+wr].
    const bool offdiag = (br != bc);
    const bool posblk  = (bc == br + 32);
    float colsum[4] = {0.f, 0.f, 0.f, 0.f};

    #pragma unroll
    for (int mf = 0; mf < 4; ++mf) {
        float rs[4] = {0.f, 0.f, 0.f, 0.f};
        const int rowq = br * 128 + wr * 64 + mf * 16 + kl * 4;
        #pragma unroll
        for (int nf = 0; nf < 4; ++nf) {
            const int col = bc * 128 + wc * 64 + nf * 16 + fr;
            f32x4 a = acc[mf][nf];
            #pragma unroll
            for (int j = 0; j < 4; ++j) {
                float e = (rowq + j == col) ? 0.f : __expf((a[j] - 1.0f) * INV_T);
                rs[j]      += e;
                colsum[nf] += e;
                if (posblk && (rowq + j + 4096 == col)) {
                    pos[rowq + j] = a[j];
                    pos[col]      = a[j];
                }
            }
        }
        #pragma unroll
        for (int m = 1; m < 16; m <<= 1) {
            #pragma unroll
            for (int j = 0; j < 4; ++j) rs[j] += __shfl_xor(rs[j], m, 64);
        }
        if (fr == 0) {
            float* p = partials + (size_t)rowq * 128 + bc * 2 + wc;
            p[0]   = rs[0];
            p[128] = rs[1];
            p[256] = rs[2];
            p[384] = rs[3];
        }
    }

    if (offdiag) {
        #pragma unroll
        for (int m = 16; m < 64; m <<= 1) {
            #pragma unroll
            for (int nf = 0; nf < 4; ++nf) colsum[nf] += __shfl_xor(colsum[nf], m, 64);
        }
        if (kl == 0) {
            #pragma unroll
            for (int nf = 0; nf < 4; ++nf) {
                const int col = bc * 128 + wc * 64 + nf * 16 + fr;
                partials[(size_t)col * 128 + br * 2 + wr] = colsum[nf];
            }
        }
    }
}

// ---------- kernel 3: fused loss + deterministic mean (last-block pattern) ----------
__global__ void ntx_loss(const float* __restrict__ partials, const float* __restrict__ pos,
                         float* __restrict__ bsums, u32* __restrict__ counter,
                         float* __restrict__ out)
{
    __shared__ float sm[16];
    __shared__ u32 flag;
    const int tid  = threadIdx.x;
    const int lane = tid & 63;
    const int w    = tid >> 6;       // 0..15

    float a = 0.f;
    #pragma unroll
    for (int i = 0; i < 8; ++i) {
        const int row = blockIdx.x * 128 + w * 8 + i;
        float S = partials[(size_t)row * 128 + lane] + partials[(size_t)row * 128 + 64 + lane];
        #pragma unroll
        for (int m = 1; m < 64; m <<= 1) S += __shfl_xor(S, m, 64);
        if (lane == 0) a += __logf(S) + INV_T - pos[row] * INV_T;
    }
    if (lane == 0) sm[w] = a;
    __syncthreads();

    if (tid == 0) {
        float b = 0.f;
        #pragma unroll
        for (int i = 0; i < 16; ++i) b += sm[i];
        bsums[blockIdx.x] = b;
        __threadfence();                       // release block sum
        u32 old = atomicAdd(counter, 1u);
        flag = (old == 63u) ? 1u : 0u;
    }
    __syncthreads();

    if (flag && w == 0) {                      // last block's wave 0
        __threadfence();                       // acquire all block sums
        float v = bsums[lane];
        #pragma unroll
        for (int m = 1; m < 64; m <<= 1) v += __shfl_xor(v, m, 64);
        if (lane == 0) out[0] = v * (1.0f / (float)N2);
    }
}

extern "C" void kernel_launch(void* const* d_in, const int* in_sizes, int n_in,
                              void* d_out, int out_size, void* d_ws, size_t ws_size,
                              hipStream_t stream)
{
    const float* z1 = (const float*)d_in[0];
    const float* z2 = (const float*)d_in[1];
    float* out = (float*)d_out;

    // workspace layout
    unsigned char* zn       = (unsigned char*)d_ws;                 // 8192*256  = 2 MB
    float*         partials = (float*)((char*)d_ws + (2u << 20));   // 8192*128*4 = 4 MB
    float*         pos      = (float*)((char*)d_ws + (6u << 20));   // 32 KB
    float*         bsums    = pos + N2;                             // 256 B
    u32*           counter  = (u32*)(bsums + 64);                   // 4 B

    ntx_norm<<<N2 / 4, 256, 0, stream>>>(z1, z2, zn, counter);
    ntx_gemm<<<NTRI, 256, 0, stream>>>(zn, partials, pos);
    ntx_loss<<<64, 1024, 0, stream>>>(partials, pos, bsums, counter, out);
}